// Round 9
// baseline (339.430 us; speedup 1.0000x reference)
//
#include <hip/hip_runtime.h>

typedef unsigned short u16;
typedef unsigned int   u32;
typedef __bf16 bf16x8 __attribute__((ext_vector_type(8)));
typedef float  f32x4  __attribute__((ext_vector_type(4)));
typedef _Float16 h2 __attribute__((ext_vector_type(2)));

#define M_ROWS 50000
#define M_PAD  50176    // 196 x 256
#define M_TILES 196     // 256-row tiles
#define N_REAL 1368     // 3 br * 3 tap * 152
#define N_PAD  1536
#define N_TILES 12      // 128-col tiles
#define K_DIM  300
#define K_PAD  320
#define KT     10       // K-chunks of 32
#define TROW   1368     // u16 elements per T row (2736 B, 16B-aligned)
#define SEG    152      // (br,tap) segment width; br stride 456
#define YCOL   152      // LDS ybuf row width (19 groups * 8)

#define GLDS(gp, lp) __builtin_amdgcn_global_load_lds( \
    (const __attribute__((address_space(1))) void*)(gp), \
    (__attribute__((address_space(3))) void*)(lp), 16, 0, 0)

static __device__ __forceinline__ u16 f2bf(float x){
  union { float f; u32 u; } a; a.f = x;
  u32 r = a.u + 0x7fffu + ((a.u >> 16) & 1u);   // RNE
  return (u16)(r >> 16);
}
static __device__ __forceinline__ u16 f2h(float x){
  _Float16 h = (_Float16)x;
  u16 r; __builtin_memcpy(&r, &h, 2); return r;
}
static __device__ __forceinline__ float h2f(u16 v){
  _Float16 h; __builtin_memcpy(&h, &v, 2); return (float)h;
}

// ---- DPP wave reduction: sum of all 64 lanes lands in lane 63 (6 VALU ops) ----
template<int CTRL>
static __device__ __forceinline__ float dppadd(float x){
  union { float f; int i; } a, b; a.f = x;
  b.i = __builtin_amdgcn_update_dpp(0, a.i, CTRL, 0xf, 0xf, true);
  return x + b.f;
}
static __device__ __forceinline__ float wsum63(float x){
  x = dppadd<0x111>(x);  // row_shr:1
  x = dppadd<0x112>(x);  // row_shr:2
  x = dppadd<0x114>(x);  // row_shr:4
  x = dppadd<0x118>(x);  // row_shr:8
  x = dppadd<0x142>(x);  // row_bcast:15
  x = dppadd<0x143>(x);  // row_bcast:31
  return x;              // lane 63 holds the full sum
}
static __device__ __forceinline__ float rdl63(float x){
  union { float f; int i; } a; a.f = x;
  union { int i; float f; } r; r.i = __builtin_amdgcn_readlane(a.i, 63);
  return r.f;
}

// ---------------- K1a: embedding -> swizzled bf16 A (256-row tiles) ---------------
// A u16 offset = (tile*10+kt)*8192 + mb*512 + kgl*128 + row*8 + k8; mb in 0..15.
__global__ __launch_bounds__(256) void build_A(const float* __restrict__ emb, u16* __restrict__ A){
  int t = blockIdx.x * 256 + threadIdx.x;
  if (t >= M_PAD * 40) return;
  int m = t / 40, kg = t % 40;
  int k0 = kg * 8;
  int kt = kg >> 2, kgl = kg & 3;
  int tile = m >> 8, ml = m & 255, mb = ml >> 4, row = ml & 15;
  size_t off = ((size_t)tile * KT + kt) * 8192 + mb * 512 + kgl * 128 + row * 8;
  union { uint4 q; u16 s[8]; } p;
  if (m < M_ROWS && k0 + 8 <= K_DIM){
    const float4* src = (const float4*)(emb + (size_t)m * K_DIM + k0);
    float4 v0 = src[0], v1 = src[1];
    p.s[0] = f2bf(v0.x); p.s[1] = f2bf(v0.y); p.s[2] = f2bf(v0.z); p.s[3] = f2bf(v0.w);
    p.s[4] = f2bf(v1.x); p.s[5] = f2bf(v1.y); p.s[6] = f2bf(v1.z); p.s[7] = f2bf(v1.w);
  } else {
    #pragma unroll
    for (int j = 0; j < 8; ++j){
      int k = k0 + j;
      float x = (m < M_ROWS && k < K_DIM) ? emb[(size_t)m * K_DIM + k] : 0.f;
      p.s[j] = f2bf(x);
    }
  }
  *(uint4*)(A + off) = p.q;
}

// ---------------- K1b: w1/w2/w3 -> swizzled bf16 B (SEG=152) ---------------------
// Logical B^T[n][k]: n = br*456 + tap*152 + f (f<150 real), value = w_br[tap][k][f].
__global__ void build_B(const float* __restrict__ w1, const float* __restrict__ w2,
                        const float* __restrict__ w3, u16* __restrict__ B){
  int t = blockIdx.x * 256 + threadIdx.x;
  if (t >= N_PAD * K_PAD) return;
  int n = t / K_PAD, k = t % K_PAD;
  float x = 0.f;
  if (n < N_REAL && k < K_DIM){
    int br = n / 456, rem = n % 456, tap = rem / 152, f = rem % 152;
    if (f < 150){
      const float* w = (br == 0) ? w1 : ((br == 1) ? w2 : w3);
      x = w[(tap * K_DIM + k) * 150 + f];
    }
  }
  int tn = n >> 7, nl = n & 127, nb = nl >> 4, col = nl & 15;
  int kt = k >> 5, kl = k & 31, kg = kl >> 3, k8 = kl & 7;
  B[((size_t)tn * KT + kt) * 4096 + nb * 512 + kg * 128 + col * 8 + k8] = f2bf(x);
}

// ---------------- K2: T = A x B^T  (256x128 block, 512 thr, wave-tile 64x64) ------
// 8 waves (4 m x 2 n), BK=64 (5 staging rounds), LDS 48 KB, 2 blocks/CU.
// Halves block-rounds/CU vs 128-tile -> LDS-pipe time ~halved.
__global__ __launch_bounds__(512, 4) void gemm_k(const u16* __restrict__ A, const u16* __restrict__ B,
                                                 u16* __restrict__ T){
  __shared__ __align__(16) u16 lA[16384];   // 32 KB: 2 kt-chunks x 8192 u16
  __shared__ __align__(16) u16 lB[8192];    // 16 KB: 2 kt-chunks x 4096 u16
  const int tn = blockIdx.x, tile = blockIdx.y;
  const int tid = threadIdx.x, wave = tid >> 6, lane = tid & 63;
  const int wm = wave >> 1, wn = wave & 1;
  f32x4 acc[4][4];
  #pragma unroll
  for (int i = 0; i < 4; ++i)
    #pragma unroll
    for (int j = 0; j < 4; ++j) acc[i][j] = (f32x4){0.f, 0.f, 0.f, 0.f};
  const u16* Ab = A + (size_t)tile * KT * 8192;
  const u16* Bb = B + (size_t)tn * KT * 4096;
  for (int rd = 0; rd < 5; ++rd){
    __syncthreads();
    #pragma unroll
    for (int j = 0; j < 4; ++j)
      GLDS(Ab + rd * 16384 + j * 4096 + tid * 8, lA + j * 4096 + tid * 8);
    #pragma unroll
    for (int j = 0; j < 2; ++j)
      GLDS(Bb + rd * 8192 + j * 4096 + tid * 8, lB + j * 4096 + tid * 8);
    __syncthreads();
    #pragma unroll
    for (int kk = 0; kk < 2; ++kk){
      const bf16x8* A8 = (const bf16x8*)(lA + kk * 8192);
      const bf16x8* B8 = (const bf16x8*)(lB + kk * 4096);
      bf16x8 av[4], bv[4];
      #pragma unroll
      for (int i = 0; i < 4; ++i) av[i] = A8[(wm * 4 + i) * 64 + lane];
      #pragma unroll
      for (int j = 0; j < 4; ++j) bv[j] = B8[(wn * 4 + j) * 64 + lane];
      #pragma unroll
      for (int i = 0; i < 4; ++i)
        #pragma unroll
        for (int j = 0; j < 4; ++j)
          acc[i][j] = __builtin_amdgcn_mfma_f32_16x16x32_bf16(av[i], bv[j], acc[i][j], 0, 0, 0);
    }
  }
  const int r0 = (lane >> 4) * 4, c0 = lane & 15;   // C/D: col=lane&15, row=(lane>>4)*4+reg
  #pragma unroll
  for (int i = 0; i < 4; ++i){
    int m0 = tile * 256 + wm * 64 + i * 16 + r0;
    #pragma unroll
    for (int j = 0; j < 4; ++j){
      int n0 = tn * 128 + wn * 64 + j * 16 + c0;
      if (n0 < N_REAL){
        #pragma unroll
        for (int r = 0; r < 4; ++r){
          int m = m0 + r;
          if (m < M_ROWS) T[(size_t)m * TROW + n0] = f2h(acc[i][j][r]);   // T is fp16
        }
      }
    }
  }
}

// ---------------- K3: per-title encoder (640 thr = 10 waves, 3 words/wave) --------
__global__ __launch_bounds__(640, 8) void encode_k(
    const int* __restrict__ cand, const int* __restrict__ clk,
    const u16* __restrict__ T,
    const float* __restrict__ b1, const float* __restrict__ b2, const float* __restrict__ b3,
    const float* __restrict__ lng, const float* __restrict__ lnb,
    const float* __restrict__ ql, const float* __restrict__ qw,
    float* __restrict__ rc, float* __restrict__ rh){
  __shared__ __align__(16) u16 ybuf[90][YCOL];   // summed f16 y (27.4 KB)
  __shared__ float tl[30];
  __shared__ float pbuf[10][YCOL];
  __shared__ int words[30];
  const int t = blockIdx.x;
  const int tid = threadIdx.x, wave = tid >> 6, lane = tid & 63;
  const int* wp; float* outp;
  if (t < 320){ wp = cand + t * 30;                outp = rc + t * 150; }
  else        { wp = clk + (size_t)(t - 320) * 30; outp = rh + (size_t)(t - 320) * 150; }
  if (tid < 30) words[tid] = wp[tid];
  __syncthreads();
  const float invs = 0.057735026918962576f;  // 1/sqrt(300)
  const int f0 = lane, f1 = lane + 64, f2 = lane + 128;
  const bool has2 = (f2 < 150);

  // ---- phase 0: gather; 3 taps summed via v_pk_add_f16; raw 16B store to LDS ----
  #pragma unroll
  for (int it = 0; it < 3; ++it){
    int item = tid + it * 640;
    if (item < 1710){
      int p = item / 19, fg = item - p * 19;    // p = l*3+br
      int l = p / 3, br = p - l * 3, dil = br + 1;
      union { uint4 q; h2 h[4]; } s; s.q = (uint4){0u, 0u, 0u, 0u};
      #pragma unroll
      for (int tap = 0; tap < 3; ++tap){
        int ls = l + (tap - 1) * dil;
        if (ls >= 0 && ls < 30){
          union { uint4 q; h2 h[4]; } v;
          v.q = *(const uint4*)(T + (size_t)words[ls] * TROW + br * 456 + tap * SEG + fg * 8);
          #pragma unroll
          for (int i = 0; i < 4; ++i) s.h[i] += v.h[i];   // v_pk_add_f16
        }
      }
      *(uint4*)&ybuf[p][fg * 8] = s.q;
    }
  }

  // preload per-lane params (uniform across words)
  float qlv0 = ql[f0], qlv1 = ql[f1], qlv2 = has2 ? ql[f2] : 0.f;
  float qwv0 = qw[f0], qwv1 = qw[f1], qwv2 = has2 ? qw[f2] : 0.f;
  float lg0 = lng[f0], lg1 = lng[f1], lg2 = has2 ? lng[f2] : 0.f;
  float lb0 = lnb[f0], lb1 = lnb[f1], lb2 = has2 ? lnb[f2] : 0.f;
  float bs[3][3];
  {
    const float* bl[3] = {b1, b2, b3};
    #pragma unroll
    for (int br = 0; br < 3; ++br){
      bs[br][0] = bl[br][f0]; bs[br][1] = bl[br][f1]; bs[br][2] = has2 ? bl[br][f2] : 0.f;
    }
  }
  __syncthreads();

  // ---- phase 1: word-major LN + level-attn (d in regs, DPP reduces); 3 words/wave ----
  float at0[3], at1[3], at2[3]; int myl[3]; int nw = 0;
  for (int l = wave; l < 30; l += 10){
    float dr[3][3]; float lvl[3];
    #pragma unroll
    for (int br = 0; br < 3; ++br){
      int p = l * 3 + br;
      float y0 = h2f(ybuf[p][f0]) + bs[br][0];
      float y1 = h2f(ybuf[p][f1]) + bs[br][1];
      float y2 = has2 ? (h2f(ybuf[p][f2]) + bs[br][2]) : 0.f;
      float s  = y0 + y1 + y2;
      float ss = y0 * y0 + y1 * y1 + y2 * y2;
      float st = wsum63(s), sst = wsum63(ss);
      float mean = rdl63(st) * (1.f / 150.f);
      float var  = rdl63(sst) * (1.f / 150.f) - mean * mean;
      float rstd = rsqrtf(var + 1e-5f);
      float d0 = fmaxf((y0 - mean) * rstd * lg0 + lb0, 0.f);
      float d1 = fmaxf((y1 - mean) * rstd * lg1 + lb1, 0.f);
      float d2 = has2 ? fmaxf((y2 - mean) * rstd * lg2 + lb2, 0.f) : 0.f;
      dr[br][0] = d0; dr[br][1] = d1; dr[br][2] = d2;
      float dot = qlv0 * d0 + qlv1 * d1 + qlv2 * d2;
      lvl[br] = rdl63(wsum63(dot)) * invs;
    }
    // wave-local level softmax
    float mx = fmaxf(lvl[0], fmaxf(lvl[1], lvl[2]));
    float e0 = expf(lvl[0] - mx), e1 = expf(lvl[1] - mx), e2 = expf(lvl[2] - mx);
    float inv = 1.f / (e0 + e1 + e2);
    float w0 = e0 * inv, w1v = e1 * inv, w2v = e2 * inv;
    float a0 = w0 * dr[0][0] + w1v * dr[1][0] + w2v * dr[2][0];
    float a1 = w0 * dr[0][1] + w1v * dr[1][1] + w2v * dr[2][1];
    float a2 = w0 * dr[0][2] + w1v * dr[1][2] + w2v * dr[2][2];
    float dot = qwv0 * a0 + qwv1 * a1 + qwv2 * a2;
    float tw = wsum63(dot);
    if (lane == 63) tl[l] = tw * invs;
    at0[nw] = a0; at1[nw] = a1; at2[nw] = a2; myl[nw] = l; ++nw;
  }
  __syncthreads();

  // ---- phase 2: word softmax + per-wave partial reprs ----
  float mx = -1e30f;
  for (int l = 0; l < 30; ++l) mx = fmaxf(mx, tl[l]);
  float den = 0.f;
  for (int l = 0; l < 30; ++l) den += expf(tl[l] - mx);
  float invden = 1.f / den;
  float p0 = 0.f, p1 = 0.f, p2 = 0.f;
  for (int q = 0; q < nw; ++q){
    float wwv = expf(tl[myl[q]] - mx) * invden;
    p0 += wwv * at0[q]; p1 += wwv * at1[q]; p2 += wwv * at2[q];
  }
  pbuf[wave][lane] = p0;
  pbuf[wave][lane + 64] = p1;
  if (has2) pbuf[wave][lane + 128] = p2;
  __syncthreads();
  if (tid < 150){
    float acc = 0.f;
    #pragma unroll
    for (int w = 0; w < 10; ++w) acc += pbuf[w][tid];
    outp[tid] = acc;
  }
}

// ---------------- K4: scores -> logits -> log_softmax (LDS-staged) ----------------
__global__ __launch_bounds__(256) void final_k(const float* __restrict__ rc, const float* __restrict__ rh,
                                               const float* __restrict__ lw, const float* __restrict__ lb,
                                               float* __restrict__ out){
  __shared__ float Cl[750];
  __shared__ float Hl[7500];
  __shared__ float sc[5][52];
  __shared__ float lg[5];
  const int b = blockIdx.x, tid = threadIdx.x;
  const float* C = rc + b * 750;
  const float* H = rh + (size_t)b * 7500;
  for (int i = tid; i < 750; i += 256) Cl[i] = C[i];
  for (int i = tid; i < 7500; i += 256) Hl[i] = H[i];
  __syncthreads();
  if (tid < 250){
    int c = tid / 50, h = tid % 50;
    float s = 0.f;
    #pragma unroll 10
    for (int k = 0; k < 150; ++k) s += Cl[c * 150 + k] * Hl[h * 150 + k];
    sc[c][h] = s;
  }
  __syncthreads();
  if (tid < 5){
    float s = lb[0];
    for (int h = 0; h < 50; ++h) s += sc[tid][h] * lw[h];
    lg[tid] = s;
  }
  __syncthreads();
  if (tid < 5){
    float mx = fmaxf(fmaxf(fmaxf(lg[0], lg[1]), fmaxf(lg[2], lg[3])), lg[4]);
    float den = 0.f;
    for (int c = 0; c < 5; ++c) den += expf(lg[c] - mx);
    out[b * 5 + tid] = lg[tid] - mx - logf(den);
  }
}

extern "C" void kernel_launch(void* const* d_in, const int* in_sizes, int n_in,
                              void* d_out, int out_size, void* d_ws, size_t ws_size,
                              hipStream_t stream){
  const int*   cand = (const int*)d_in[0];
  const int*   clk  = (const int*)d_in[1];
  const float* emb  = (const float*)d_in[2];
  const float* w1   = (const float*)d_in[3];
  const float* b1   = (const float*)d_in[4];
  const float* w2   = (const float*)d_in[5];
  const float* b2   = (const float*)d_in[6];
  const float* w3   = (const float*)d_in[7];
  const float* b3   = (const float*)d_in[8];
  const float* lng  = (const float*)d_in[9];
  const float* lnb  = (const float*)d_in[10];
  const float* ql   = (const float*)d_in[11];
  const float* qw   = (const float*)d_in[12];
  const float* lw   = (const float*)d_in[13];
  const float* lb   = (const float*)d_in[14];
  float* out = (float*)d_out;

  char* ws = (char*)d_ws;
  const size_t szA = (size_t)M_TILES * KT * 16384;  // 32,112,640 B
  const size_t szB = (size_t)N_TILES * KT * 8192;   //     983,040 B
  const size_t szT = (size_t)M_ROWS * TROW * 2;     // 136,800,000 B
  u16*   A  = (u16*)ws;
  u16*   B  = (u16*)(ws + szA);
  u16*   T  = (u16*)(ws + szA + szB);
  float* rc = (float*)(ws + szA + szB + szT);
  float* rh = rc + 320 * 150;

  build_A<<<(M_PAD * 40 + 255) / 256, 256, 0, stream>>>(emb, A);
  build_B<<<(N_PAD * K_PAD + 255) / 256, 256, 0, stream>>>(w1, w2, w3, B);
  gemm_k<<<dim3(N_TILES, M_TILES), 512, 0, stream>>>(A, B, T);
  encode_k<<<3520, 640, 0, stream>>>(cand, clk, T, b1, b2, b3, lng, lnb, ql, qw, rc, rh);
  final_k<<<64, 256, 0, stream>>>(rc, rh, lw, lb, out);
}

// Round 10
// 323.407 us; speedup vs baseline: 1.0495x; 1.0495x over previous
//
#include <hip/hip_runtime.h>

typedef unsigned short u16;
typedef unsigned int   u32;
typedef __bf16 bf16x8 __attribute__((ext_vector_type(8)));
typedef float  f32x4  __attribute__((ext_vector_type(4)));
typedef _Float16 h2 __attribute__((ext_vector_type(2)));

#define M_ROWS 50000
#define M_PAD  50176    // 196 x 256
#define M_TILES 196     // 256-row tiles
#define N_REAL 1368     // 3 br * 3 tap * 152
#define N_PAD  1536
#define N_TILES 11      // 128-col tiles actually used (cols 0..1407)
#define K_DIM  300
#define K_PAD  320
#define KT     10       // K-chunks of 32
#define TROW   1408     // u16 elements per T row (2816 B, multiple of 128 cols)
#define SEG    152      // (br,tap) segment width; br stride 456
#define YCOL   152      // LDS ybuf row width (19 groups * 8)
#define TS     136      // gemm epilogue LDS tile stride (16B-aligned rows)

#define GLDS(gp, lp) __builtin_amdgcn_global_load_lds( \
    (const __attribute__((address_space(1))) void*)(gp), \
    (__attribute__((address_space(3))) void*)(lp), 16, 0, 0)

static __device__ __forceinline__ u16 f2bf(float x){
  union { float f; u32 u; } a; a.f = x;
  u32 r = a.u + 0x7fffu + ((a.u >> 16) & 1u);   // RNE
  return (u16)(r >> 16);
}
static __device__ __forceinline__ u16 f2h(float x){
  _Float16 h = (_Float16)x;
  u16 r; __builtin_memcpy(&r, &h, 2); return r;
}
static __device__ __forceinline__ float h2f(u16 v){
  _Float16 h; __builtin_memcpy(&h, &v, 2); return (float)h;
}

// ---- DPP wave reduction: sum of all 64 lanes lands in lane 63 (6 VALU ops) ----
template<int CTRL>
static __device__ __forceinline__ float dppadd(float x){
  union { float f; int i; } a, b; a.f = x;
  b.i = __builtin_amdgcn_update_dpp(0, a.i, CTRL, 0xf, 0xf, true);
  return x + b.f;
}
static __device__ __forceinline__ float wsum63(float x){
  x = dppadd<0x111>(x);  // row_shr:1
  x = dppadd<0x112>(x);  // row_shr:2
  x = dppadd<0x114>(x);  // row_shr:4
  x = dppadd<0x118>(x);  // row_shr:8
  x = dppadd<0x142>(x);  // row_bcast:15
  x = dppadd<0x143>(x);  // row_bcast:31
  return x;              // lane 63 holds the full sum
}
static __device__ __forceinline__ float rdl63(float x){
  union { float f; int i; } a; a.f = x;
  union { int i; float f; } r; r.i = __builtin_amdgcn_readlane(a.i, 63);
  return r.f;
}

// ---------------- K1a: embedding -> swizzled bf16 A (256-row tiles) ---------------
__global__ __launch_bounds__(256) void build_A(const float* __restrict__ emb, u16* __restrict__ A){
  int t = blockIdx.x * 256 + threadIdx.x;
  if (t >= M_PAD * 40) return;
  int m = t / 40, kg = t % 40;
  int k0 = kg * 8;
  int kt = kg >> 2, kgl = kg & 3;
  int tile = m >> 8, ml = m & 255, mb = ml >> 4, row = ml & 15;
  size_t off = ((size_t)tile * KT + kt) * 8192 + mb * 512 + kgl * 128 + row * 8;
  union { uint4 q; u16 s[8]; } p;
  if (m < M_ROWS && k0 + 8 <= K_DIM){
    const float4* src = (const float4*)(emb + (size_t)m * K_DIM + k0);
    float4 v0 = src[0], v1 = src[1];
    p.s[0] = f2bf(v0.x); p.s[1] = f2bf(v0.y); p.s[2] = f2bf(v0.z); p.s[3] = f2bf(v0.w);
    p.s[4] = f2bf(v1.x); p.s[5] = f2bf(v1.y); p.s[6] = f2bf(v1.z); p.s[7] = f2bf(v1.w);
  } else {
    #pragma unroll
    for (int j = 0; j < 8; ++j){
      int k = k0 + j;
      float x = (m < M_ROWS && k < K_DIM) ? emb[(size_t)m * K_DIM + k] : 0.f;
      p.s[j] = f2bf(x);
    }
  }
  *(uint4*)(A + off) = p.q;
}

// ---------------- K1b: w1/w2/w3 -> swizzled bf16 B (SEG=152) ---------------------
__global__ void build_B(const float* __restrict__ w1, const float* __restrict__ w2,
                        const float* __restrict__ w3, u16* __restrict__ B){
  int t = blockIdx.x * 256 + threadIdx.x;
  if (t >= N_PAD * K_PAD) return;
  int n = t / K_PAD, k = t % K_PAD;
  float x = 0.f;
  if (n < N_REAL && k < K_DIM){
    int br = n / 456, rem = n % 456, tap = rem / 152, f = rem % 152;
    if (f < 150){
      const float* w = (br == 0) ? w1 : ((br == 1) ? w2 : w3);
      x = w[(tap * K_DIM + k) * 150 + f];
    }
  }
  int tn = n >> 7, nl = n & 127, nb = nl >> 4, col = nl & 15;
  int kt = k >> 5, kl = k & 31, kg = kl >> 3, k8 = kl & 7;
  B[((size_t)tn * KT + kt) * 4096 + nb * 512 + kg * 128 + col * 8 + k8] = f2bf(x);
}

// ---------------- K2: T = A x B^T  (256x128 block, BK=64, coalesced epilogue) -----
__global__ __launch_bounds__(512, 4) void gemm_k(const u16* __restrict__ A, const u16* __restrict__ B,
                                                 u16* __restrict__ T){
  __shared__ __align__(16) u16 lds[24576];  // 48 KB: lA 32KB | lB 16KB; epilogue tile 128xTS
  u16* lA = lds;
  u16* lB = lds + 16384;
  const int tn = blockIdx.x, tileM = blockIdx.y;
  const int tid = threadIdx.x, wave = tid >> 6, lane = tid & 63;
  const int wm = wave >> 1, wn = wave & 1;
  f32x4 acc[4][4];
  #pragma unroll
  for (int i = 0; i < 4; ++i)
    #pragma unroll
    for (int j = 0; j < 4; ++j) acc[i][j] = (f32x4){0.f, 0.f, 0.f, 0.f};
  const u16* Ab = A + (size_t)tileM * KT * 8192;
  const u16* Bb = B + (size_t)tn * KT * 4096;
  for (int rd = 0; rd < 5; ++rd){
    __syncthreads();
    #pragma unroll
    for (int j = 0; j < 4; ++j)
      GLDS(Ab + rd * 16384 + j * 4096 + tid * 8, lA + j * 4096 + tid * 8);
    #pragma unroll
    for (int j = 0; j < 2; ++j)
      GLDS(Bb + rd * 8192 + j * 4096 + tid * 8, lB + j * 4096 + tid * 8);
    __syncthreads();
    #pragma unroll
    for (int kk = 0; kk < 2; ++kk){
      const bf16x8* A8 = (const bf16x8*)(lA + kk * 8192);
      const bf16x8* B8 = (const bf16x8*)(lB + kk * 4096);
      bf16x8 av[4], bv[4];
      #pragma unroll
      for (int i = 0; i < 4; ++i) av[i] = A8[(wm * 4 + i) * 64 + lane];
      #pragma unroll
      for (int j = 0; j < 4; ++j) bv[j] = B8[(wn * 4 + j) * 64 + lane];
      #pragma unroll
      for (int i = 0; i < 4; ++i)
        #pragma unroll
        for (int j = 0; j < 4; ++j)
          acc[i][j] = __builtin_amdgcn_mfma_f32_16x16x32_bf16(av[i], bv[j], acc[i][j], 0, 0, 0);
    }
  }
  // epilogue: per 128-row half, stage f16 tile in LDS then coalesced dwordx4 stores
  const int r0 = (lane >> 4) * 4, c0 = lane & 15;   // C/D: col=lane&15, row=(lane>>4)*4+reg
  const int row = tid >> 2, q = tid & 3;
  #pragma unroll
  for (int half = 0; half < 2; ++half){
    __syncthreads();
    if ((wm >> 1) == half){
      const int rbase = (wm & 1) * 64;
      #pragma unroll
      for (int i = 0; i < 4; ++i){
        #pragma unroll
        for (int j = 0; j < 4; ++j){
          int col = wn * 64 + j * 16 + c0;
          #pragma unroll
          for (int r = 0; r < 4; ++r)
            lds[(rbase + i * 16 + r0 + r) * TS + col] = f2h(acc[i][j][r]);
        }
      }
    }
    __syncthreads();
    int m = tileM * 256 + half * 128 + row;
    if (m < M_ROWS){
      const u16* src = lds + row * TS + q * 32;
      u16* dst = T + (size_t)m * TROW + tn * 128 + q * 32;
      uint4 v0 = *(const uint4*)(src);
      uint4 v1 = *(const uint4*)(src + 8);
      uint4 v2 = *(const uint4*)(src + 16);
      uint4 v3 = *(const uint4*)(src + 24);
      *(uint4*)(dst)      = v0;
      *(uint4*)(dst + 8)  = v1;
      *(uint4*)(dst + 16) = v2;
      *(uint4*)(dst + 24) = v3;
    }
  }
}

// ---------------- K3: per-title encoder (512 thr, word-major, DPP reductions) ------
__global__ __launch_bounds__(512, 8) void encode_k(
    const int* __restrict__ cand, const int* __restrict__ clk,
    const u16* __restrict__ T,
    const float* __restrict__ b1, const float* __restrict__ b2, const float* __restrict__ b3,
    const float* __restrict__ lng, const float* __restrict__ lnb,
    const float* __restrict__ ql, const float* __restrict__ qw,
    float* __restrict__ rc, float* __restrict__ rh){
  __shared__ __align__(16) u16 ybuf[90][YCOL];   // summed f16 y (27.4 KB)
  __shared__ float tl[30];
  __shared__ float pbuf[8][YCOL];
  __shared__ u32 wordoff[30];
  const int t = blockIdx.x;
  const int tid = threadIdx.x, wave = tid >> 6, lane = tid & 63;
  const int* wp; float* outp;
  if (t < 320){ wp = cand + t * 30;                outp = rc + t * 150; }
  else        { wp = clk + (size_t)(t - 320) * 30; outp = rh + (size_t)(t - 320) * 150; }
  if (tid < 30) wordoff[tid] = (u32)wp[tid] * (u32)TROW;
  __syncthreads();
  const float invs = 0.057735026918962576f;  // 1/sqrt(300)
  const int f0 = lane, f1 = lane + 64, f2 = lane + 128;
  const bool has2 = (f2 < 150);

  // ---- phase 0: gather; 3 taps summed via v_pk_add_f16; raw 16B store to LDS ----
  #pragma unroll
  for (int it = 0; it < 4; ++it){
    int item = tid + it * 512;
    if (item < 1710){
      int p = item / 19, fg = item - p * 19;    // p = l*3+br
      int l = p / 3, br = p - l * 3, dil = br + 1;
      union { uint4 q; h2 h[4]; } s; s.q = (uint4){0u, 0u, 0u, 0u};
      #pragma unroll
      for (int tap = 0; tap < 3; ++tap){
        int ls = l + (tap - 1) * dil;
        if (ls >= 0 && ls < 30){
          union { uint4 q; h2 h[4]; } v;
          v.q = *(const uint4*)(T + wordoff[ls] + br * 456 + tap * SEG + fg * 8);
          #pragma unroll
          for (int i = 0; i < 4; ++i) s.h[i] += v.h[i];   // v_pk_add_f16
        }
      }
      *(uint4*)&ybuf[p][fg * 8] = s.q;
    }
  }

  // preload per-lane params (uniform across words)
  float qlv0 = ql[f0], qlv1 = ql[f1], qlv2 = has2 ? ql[f2] : 0.f;
  float qwv0 = qw[f0], qwv1 = qw[f1], qwv2 = has2 ? qw[f2] : 0.f;
  float lg0 = lng[f0], lg1 = lng[f1], lg2 = has2 ? lng[f2] : 0.f;
  float lb0 = lnb[f0], lb1 = lnb[f1], lb2 = has2 ? lnb[f2] : 0.f;
  float bs[3][3];
  {
    const float* bl[3] = {b1, b2, b3};
    #pragma unroll
    for (int br = 0; br < 3; ++br){
      bs[br][0] = bl[br][f0]; bs[br][1] = bl[br][f1]; bs[br][2] = has2 ? bl[br][f2] : 0.f;
    }
  }
  __syncthreads();

  // ---- phase 1: word-major LN + level-attn (d in regs, DPP reduces) ----
  float at0[4], at1[4], at2[4]; int myl[4]; int nw = 0;
  for (int l = wave; l < 30; l += 8){
    float dr[3][3]; float lvl[3];
    #pragma unroll
    for (int br = 0; br < 3; ++br){
      int p = l * 3 + br;
      float y0 = h2f(ybuf[p][f0]) + bs[br][0];
      float y1 = h2f(ybuf[p][f1]) + bs[br][1];
      float y2 = has2 ? (h2f(ybuf[p][f2]) + bs[br][2]) : 0.f;
      float s  = y0 + y1 + y2;
      float ss = y0 * y0 + y1 * y1 + y2 * y2;
      float st = wsum63(s), sst = wsum63(ss);
      float mean = rdl63(st) * (1.f / 150.f);
      float var  = rdl63(sst) * (1.f / 150.f) - mean * mean;
      float rstd = rsqrtf(var + 1e-5f);
      float d0 = fmaxf((y0 - mean) * rstd * lg0 + lb0, 0.f);
      float d1 = fmaxf((y1 - mean) * rstd * lg1 + lb1, 0.f);
      float d2 = has2 ? fmaxf((y2 - mean) * rstd * lg2 + lb2, 0.f) : 0.f;
      dr[br][0] = d0; dr[br][1] = d1; dr[br][2] = d2;
      float dot = qlv0 * d0 + qlv1 * d1 + qlv2 * d2;
      lvl[br] = rdl63(wsum63(dot)) * invs;
    }
    // wave-local level softmax
    float mx = fmaxf(lvl[0], fmaxf(lvl[1], lvl[2]));
    float e0 = expf(lvl[0] - mx), e1 = expf(lvl[1] - mx), e2 = expf(lvl[2] - mx);
    float inv = 1.f / (e0 + e1 + e2);
    float w0 = e0 * inv, w1v = e1 * inv, w2v = e2 * inv;
    float a0 = w0 * dr[0][0] + w1v * dr[1][0] + w2v * dr[2][0];
    float a1 = w0 * dr[0][1] + w1v * dr[1][1] + w2v * dr[2][1];
    float a2 = w0 * dr[0][2] + w1v * dr[1][2] + w2v * dr[2][2];
    float dot = qwv0 * a0 + qwv1 * a1 + qwv2 * a2;
    float tw = wsum63(dot);
    if (lane == 63) tl[l] = tw * invs;
    at0[nw] = a0; at1[nw] = a1; at2[nw] = a2; myl[nw] = l; ++nw;
  }
  __syncthreads();

  // ---- phase 2: word softmax + per-wave partial reprs ----
  float mx = -1e30f;
  for (int l = 0; l < 30; ++l) mx = fmaxf(mx, tl[l]);
  float den = 0.f;
  for (int l = 0; l < 30; ++l) den += expf(tl[l] - mx);
  float invden = 1.f / den;
  float p0 = 0.f, p1 = 0.f, p2 = 0.f;
  for (int q = 0; q < nw; ++q){
    float wwv = expf(tl[myl[q]] - mx) * invden;
    p0 += wwv * at0[q]; p1 += wwv * at1[q]; p2 += wwv * at2[q];
  }
  pbuf[wave][lane] = p0;
  pbuf[wave][lane + 64] = p1;
  if (has2) pbuf[wave][lane + 128] = p2;
  __syncthreads();
  if (tid < 150){
    float acc = 0.f;
    #pragma unroll
    for (int w = 0; w < 8; ++w) acc += pbuf[w][tid];
    outp[tid] = acc;
  }
}

// ---------------- K4: scores -> logits -> log_softmax (LDS-staged) ----------------
__global__ __launch_bounds__(256) void final_k(const float* __restrict__ rc, const float* __restrict__ rh,
                                               const float* __restrict__ lw, const float* __restrict__ lb,
                                               float* __restrict__ out){
  __shared__ float Cl[750];
  __shared__ float Hl[7500];
  __shared__ float sc[5][52];
  __shared__ float lg[5];
  const int b = blockIdx.x, tid = threadIdx.x;
  const float* C = rc + b * 750;
  const float* H = rh + (size_t)b * 7500;
  for (int i = tid; i < 750; i += 256) Cl[i] = C[i];
  for (int i = tid; i < 7500; i += 256) Hl[i] = H[i];
  __syncthreads();
  if (tid < 250){
    int c = tid / 50, h = tid % 50;
    float s = 0.f;
    #pragma unroll 10
    for (int k = 0; k < 150; ++k) s += Cl[c * 150 + k] * Hl[h * 150 + k];
    sc[c][h] = s;
  }
  __syncthreads();
  if (tid < 5){
    float s = lb[0];
    for (int h = 0; h < 50; ++h) s += sc[tid][h] * lw[h];
    lg[tid] = s;
  }
  __syncthreads();
  if (tid < 5){
    float mx = fmaxf(fmaxf(fmaxf(lg[0], lg[1]), fmaxf(lg[2], lg[3])), lg[4]);
    float den = 0.f;
    for (int c = 0; c < 5; ++c) den += expf(lg[c] - mx);
    out[b * 5 + tid] = lg[tid] - mx - logf(den);
  }
}

extern "C" void kernel_launch(void* const* d_in, const int* in_sizes, int n_in,
                              void* d_out, int out_size, void* d_ws, size_t ws_size,
                              hipStream_t stream){
  const int*   cand = (const int*)d_in[0];
  const int*   clk  = (const int*)d_in[1];
  const float* emb  = (const float*)d_in[2];
  const float* w1   = (const float*)d_in[3];
  const float* b1   = (const float*)d_in[4];
  const float* w2   = (const float*)d_in[5];
  const float* b2   = (const float*)d_in[6];
  const float* w3   = (const float*)d_in[7];
  const float* b3   = (const float*)d_in[8];
  const float* lng  = (const float*)d_in[9];
  const float* lnb  = (const float*)d_in[10];
  const float* ql   = (const float*)d_in[11];
  const float* qw   = (const float*)d_in[12];
  const float* lw   = (const float*)d_in[13];
  const float* lb   = (const float*)d_in[14];
  float* out = (float*)d_out;

  char* ws = (char*)d_ws;
  const size_t szA = (size_t)M_TILES * KT * 16384;  // 32,112,640 B
  const size_t szB = (size_t)12 * KT * 8192;        //     983,040 B
  const size_t szT = (size_t)M_ROWS * TROW * 2;     // 140,800,000 B
  u16*   A  = (u16*)ws;
  u16*   B  = (u16*)(ws + szA);
  u16*   T  = (u16*)(ws + szA + szB);
  float* rc = (float*)(ws + szA + szB + szT);
  float* rh = rc + 320 * 150;

  build_A<<<(M_PAD * 40 + 255) / 256, 256, 0, stream>>>(emb, A);
  build_B<<<(N_PAD * K_PAD + 255) / 256, 256, 0, stream>>>(w1, w2, w3, B);
  gemm_k<<<dim3(N_TILES, M_TILES), 512, 0, stream>>>(A, B, T);
  encode_k<<<3520, 512, 0, stream>>>(cand, clk, T, b1, b2, b3, lng, lnb, ql, qw, rc, rh);
  final_k<<<64, 256, 0, stream>>>(rc, rh, lw, lb, out);
}

// Round 11
// 299.157 us; speedup vs baseline: 1.1346x; 1.0811x over previous
//
#include <hip/hip_runtime.h>

typedef unsigned short u16;
typedef unsigned int   u32;
typedef __bf16 bf16x8 __attribute__((ext_vector_type(8)));
typedef float  f32x4  __attribute__((ext_vector_type(4)));
typedef _Float16 h2 __attribute__((ext_vector_type(2)));

#define M_ROWS 50000
#define M_PAD  50176    // 196 x 256
#define M_TILES 196     // 256-row tiles
#define N_REAL 1368     // 3 br * 3 tap * 152
#define N_PAD  1536
#define N_TILES 11      // 128-col tiles actually used (cols 0..1407)
#define K_DIM  300
#define K_PAD  320
#define KT     10       // K-chunks of 32
#define TROW   1408     // u16 elements per T row (2816 B, multiple of 128 cols)
#define SEG    152      // (br,tap) segment width; br stride 456
#define YCOL   152      // LDS ybuf row width (19 groups * 8)
#define TS     136      // gemm epilogue LDS tile stride (16B-aligned rows)

#define GLDS(gp, lp) __builtin_amdgcn_global_load_lds( \
    (const __attribute__((address_space(1))) void*)(gp), \
    (__attribute__((address_space(3))) void*)(lp), 16, 0, 0)

static __device__ __forceinline__ u16 f2bf(float x){
  union { float f; u32 u; } a; a.f = x;
  u32 r = a.u + 0x7fffu + ((a.u >> 16) & 1u);   // RNE
  return (u16)(r >> 16);
}
static __device__ __forceinline__ u16 f2h(float x){
  _Float16 h = (_Float16)x;
  u16 r; __builtin_memcpy(&r, &h, 2); return r;
}
static __device__ __forceinline__ float h2f(u16 v){
  _Float16 h; __builtin_memcpy(&h, &v, 2); return (float)h;
}

// ---- DPP wave reductions via raw asm (6 VALU inst; s_nop covers DPP wait states).
// Sum of all 64 lanes lands in lane 63 (canonical gfx9 sequence, in-place).
static __device__ __forceinline__ float wsum63(float x){
  asm volatile(
    "s_nop 1\n\t"
    "v_add_f32 %0, %0, %0 row_shr:1 bound_ctrl:0\n\t"
    "s_nop 1\n\t"
    "v_add_f32 %0, %0, %0 row_shr:2 bound_ctrl:0\n\t"
    "s_nop 1\n\t"
    "v_add_f32 %0, %0, %0 row_shr:4 bound_ctrl:0\n\t"
    "s_nop 1\n\t"
    "v_add_f32 %0, %0, %0 row_shr:8 bound_ctrl:0\n\t"
    "s_nop 1\n\t"
    "v_add_f32 %0, %0, %0 row_bcast:15 row_mask:0xa\n\t"
    "s_nop 1\n\t"
    "v_add_f32 %0, %0, %0 row_bcast:31 row_mask:0xc\n\t"
    "s_nop 1"
    : "+v"(x));
  return x;
}
// Max of all 64 lanes lands in lane 63 (in-place; unwritten lanes keep value).
static __device__ __forceinline__ float wmax63(float x){
  asm volatile(
    "s_nop 1\n\t"
    "v_max_f32 %0, %0, %0 row_shr:1\n\t"
    "s_nop 1\n\t"
    "v_max_f32 %0, %0, %0 row_shr:2\n\t"
    "s_nop 1\n\t"
    "v_max_f32 %0, %0, %0 row_shr:4\n\t"
    "s_nop 1\n\t"
    "v_max_f32 %0, %0, %0 row_shr:8\n\t"
    "s_nop 1\n\t"
    "v_max_f32 %0, %0, %0 row_bcast:15 row_mask:0xa\n\t"
    "s_nop 1\n\t"
    "v_max_f32 %0, %0, %0 row_bcast:31 row_mask:0xc\n\t"
    "s_nop 1"
    : "+v"(x));
  return x;
}
static __device__ __forceinline__ float rdl63(float x){
  union { float f; int i; } a; a.f = x;
  union { int i; float f; } r; r.i = __builtin_amdgcn_readlane(a.i, 63);
  return r.f;
}

// ---------------- K1a: embedding -> swizzled bf16 A (256-row tiles) ---------------
__global__ __launch_bounds__(256) void build_A(const float* __restrict__ emb, u16* __restrict__ A){
  int t = blockIdx.x * 256 + threadIdx.x;
  if (t >= M_PAD * 40) return;
  int m = t / 40, kg = t % 40;
  int k0 = kg * 8;
  int kt = kg >> 2, kgl = kg & 3;
  int tile = m >> 8, ml = m & 255, mb = ml >> 4, row = ml & 15;
  size_t off = ((size_t)tile * KT + kt) * 8192 + mb * 512 + kgl * 128 + row * 8;
  union { uint4 q; u16 s[8]; } p;
  if (m < M_ROWS && k0 + 8 <= K_DIM){
    const float4* src = (const float4*)(emb + (size_t)m * K_DIM + k0);
    float4 v0 = src[0], v1 = src[1];
    p.s[0] = f2bf(v0.x); p.s[1] = f2bf(v0.y); p.s[2] = f2bf(v0.z); p.s[3] = f2bf(v0.w);
    p.s[4] = f2bf(v1.x); p.s[5] = f2bf(v1.y); p.s[6] = f2bf(v1.z); p.s[7] = f2bf(v1.w);
  } else {
    #pragma unroll
    for (int j = 0; j < 8; ++j){
      int k = k0 + j;
      float x = (m < M_ROWS && k < K_DIM) ? emb[(size_t)m * K_DIM + k] : 0.f;
      p.s[j] = f2bf(x);
    }
  }
  *(uint4*)(A + off) = p.q;
}

// ---------------- K1b: w1/w2/w3 -> swizzled bf16 B (SEG=152) ---------------------
__global__ void build_B(const float* __restrict__ w1, const float* __restrict__ w2,
                        const float* __restrict__ w3, u16* __restrict__ B){
  int t = blockIdx.x * 256 + threadIdx.x;
  if (t >= N_PAD * K_PAD) return;
  int n = t / K_PAD, k = t % K_PAD;
  float x = 0.f;
  if (n < N_REAL && k < K_DIM){
    int br = n / 456, rem = n % 456, tap = rem / 152, f = rem % 152;
    if (f < 150){
      const float* w = (br == 0) ? w1 : ((br == 1) ? w2 : w3);
      x = w[(tap * K_DIM + k) * 150 + f];
    }
  }
  int tn = n >> 7, nl = n & 127, nb = nl >> 4, col = nl & 15;
  int kt = k >> 5, kl = k & 31, kg = kl >> 3, k8 = kl & 7;
  B[((size_t)tn * KT + kt) * 4096 + nb * 512 + kg * 128 + col * 8 + k8] = f2bf(x);
}

// ---------------- K2: T = A x B^T  (256x128 block, BK=64, coalesced epilogue) -----
__global__ __launch_bounds__(512, 4) void gemm_k(const u16* __restrict__ A, const u16* __restrict__ B,
                                                 u16* __restrict__ T){
  __shared__ __align__(16) u16 lds[24576];  // 48 KB: lA 32KB | lB 16KB; epilogue tile 128xTS
  u16* lA = lds;
  u16* lB = lds + 16384;
  const int tn = blockIdx.x, tileM = blockIdx.y;
  const int tid = threadIdx.x, wave = tid >> 6, lane = tid & 63;
  const int wm = wave >> 1, wn = wave & 1;
  f32x4 acc[4][4];
  #pragma unroll
  for (int i = 0; i < 4; ++i)
    #pragma unroll
    for (int j = 0; j < 4; ++j) acc[i][j] = (f32x4){0.f, 0.f, 0.f, 0.f};
  const u16* Ab = A + (size_t)tileM * KT * 8192;
  const u16* Bb = B + (size_t)tn * KT * 4096;
  for (int rd = 0; rd < 5; ++rd){
    __syncthreads();
    #pragma unroll
    for (int j = 0; j < 4; ++j)
      GLDS(Ab + rd * 16384 + j * 4096 + tid * 8, lA + j * 4096 + tid * 8);
    #pragma unroll
    for (int j = 0; j < 2; ++j)
      GLDS(Bb + rd * 8192 + j * 4096 + tid * 8, lB + j * 4096 + tid * 8);
    __syncthreads();
    #pragma unroll
    for (int kk = 0; kk < 2; ++kk){
      const bf16x8* A8 = (const bf16x8*)(lA + kk * 8192);
      const bf16x8* B8 = (const bf16x8*)(lB + kk * 4096);
      bf16x8 av[4], bv[4];
      #pragma unroll
      for (int i = 0; i < 4; ++i) av[i] = A8[(wm * 4 + i) * 64 + lane];
      #pragma unroll
      for (int j = 0; j < 4; ++j) bv[j] = B8[(wn * 4 + j) * 64 + lane];
      #pragma unroll
      for (int i = 0; i < 4; ++i)
        #pragma unroll
        for (int j = 0; j < 4; ++j)
          acc[i][j] = __builtin_amdgcn_mfma_f32_16x16x32_bf16(av[i], bv[j], acc[i][j], 0, 0, 0);
    }
  }
  // epilogue: per 128-row half, stage f16 tile in LDS then coalesced dwordx4 stores
  const int r0 = (lane >> 4) * 4, c0 = lane & 15;   // C/D: col=lane&15, row=(lane>>4)*4+reg
  const int row = tid >> 2, q = tid & 3;
  #pragma unroll
  for (int half = 0; half < 2; ++half){
    __syncthreads();
    if ((wm >> 1) == half){
      const int rbase = (wm & 1) * 64;
      #pragma unroll
      for (int i = 0; i < 4; ++i){
        #pragma unroll
        for (int j = 0; j < 4; ++j){
          int col = wn * 64 + j * 16 + c0;
          #pragma unroll
          for (int r = 0; r < 4; ++r)
            lds[(rbase + i * 16 + r0 + r) * TS + col] = f2h(acc[i][j][r]);
        }
      }
    }
    __syncthreads();
    int m = tileM * 256 + half * 128 + row;
    if (m < M_ROWS){
      const u16* src = lds + row * TS + q * 32;
      u16* dst = T + (size_t)m * TROW + tn * 128 + q * 32;
      uint4 v0 = *(const uint4*)(src);
      uint4 v1 = *(const uint4*)(src + 8);
      uint4 v2 = *(const uint4*)(src + 16);
      uint4 v3 = *(const uint4*)(src + 24);
      *(uint4*)(dst)      = v0;
      *(uint4*)(dst + 8)  = v1;
      *(uint4*)(dst + 16) = v2;
      *(uint4*)(dst + 24) = v3;
    }
  }
}

// ---------------- K3: per-title encoder (512 thr, asm-DPP, softmax-once) ----------
__global__ __launch_bounds__(512, 8) void encode_k(
    const int* __restrict__ cand, const int* __restrict__ clk,
    const u16* __restrict__ T,
    const float* __restrict__ b1, const float* __restrict__ b2, const float* __restrict__ b3,
    const float* __restrict__ lng, const float* __restrict__ lnb,
    const float* __restrict__ ql, const float* __restrict__ qw,
    float* __restrict__ rc, float* __restrict__ rh){
  __shared__ __align__(16) u16 ybuf[90][YCOL];   // summed f16 y (27.4 KB)
  __shared__ float tl[32];                        // logits, then normalized ww
  __shared__ float pbuf[8][YCOL];
  __shared__ u32 wordoff[30];
  const int t = blockIdx.x;
  const int tid = threadIdx.x, wave = tid >> 6, lane = tid & 63;
  const int* wp; float* outp;
  if (t < 320){ wp = cand + t * 30;                outp = rc + t * 150; }
  else        { wp = clk + (size_t)(t - 320) * 30; outp = rh + (size_t)(t - 320) * 150; }
  if (tid < 30) wordoff[tid] = (u32)wp[tid] * (u32)TROW;
  __syncthreads();
  const float invs = 0.057735026918962576f;  // 1/sqrt(300)
  const int f0 = lane, f1 = lane + 64, f2 = lane + 128;
  const bool has2 = (f2 < 150);

  // ---- phase 0: gather; 3 taps summed via v_pk_add_f16; raw 16B store to LDS ----
  #pragma unroll
  for (int it = 0; it < 4; ++it){
    int item = tid + it * 512;
    if (item < 1710){
      int p = item / 19, fg = item - p * 19;    // p = l*3+br
      int l = p / 3, br = p - l * 3, dil = br + 1;
      union { uint4 q; h2 h[4]; } s; s.q = (uint4){0u, 0u, 0u, 0u};
      #pragma unroll
      for (int tap = 0; tap < 3; ++tap){
        int ls = l + (tap - 1) * dil;
        if (ls >= 0 && ls < 30){
          union { uint4 q; h2 h[4]; } v;
          v.q = *(const uint4*)(T + wordoff[ls] + br * 456 + tap * SEG + fg * 8);
          #pragma unroll
          for (int i = 0; i < 4; ++i) s.h[i] += v.h[i];   // v_pk_add_f16
        }
      }
      *(uint4*)&ybuf[p][fg * 8] = s.q;
    }
  }

  // preload per-lane params (uniform across words)
  float qlv0 = ql[f0], qlv1 = ql[f1], qlv2 = has2 ? ql[f2] : 0.f;
  float qwv0 = qw[f0], qwv1 = qw[f1], qwv2 = has2 ? qw[f2] : 0.f;
  float lg0 = lng[f0], lg1 = lng[f1], lg2 = has2 ? lng[f2] : 0.f;
  float lb0 = lnb[f0], lb1 = lnb[f1], lb2 = has2 ? lnb[f2] : 0.f;
  float bs[3][3];
  {
    const float* bl[3] = {b1, b2, b3};
    #pragma unroll
    for (int br = 0; br < 3; ++br){
      bs[br][0] = bl[br][f0]; bs[br][1] = bl[br][f1]; bs[br][2] = has2 ? bl[br][f2] : 0.f;
    }
  }
  __syncthreads();

  // ---- phase 1: word-major LN + level-attn (d in regs, asm-DPP reduces) ----
  float at0[4], at1[4], at2[4]; int myl[4]; int nw = 0;
  for (int l = wave; l < 30; l += 8){
    float dr[3][3]; float lvl[3];
    #pragma unroll
    for (int br = 0; br < 3; ++br){
      int p = l * 3 + br;
      float y0 = h2f(ybuf[p][f0]) + bs[br][0];
      float y1 = h2f(ybuf[p][f1]) + bs[br][1];
      float y2 = has2 ? (h2f(ybuf[p][f2]) + bs[br][2]) : 0.f;
      float s  = y0 + y1 + y2;
      float ss = y0 * y0 + y1 * y1 + y2 * y2;
      float st = wsum63(s), sst = wsum63(ss);
      float mean = rdl63(st) * (1.f / 150.f);
      float var  = rdl63(sst) * (1.f / 150.f) - mean * mean;
      float rstd = rsqrtf(var + 1e-5f);
      float d0 = fmaxf((y0 - mean) * rstd * lg0 + lb0, 0.f);
      float d1 = fmaxf((y1 - mean) * rstd * lg1 + lb1, 0.f);
      float d2 = has2 ? fmaxf((y2 - mean) * rstd * lg2 + lb2, 0.f) : 0.f;
      dr[br][0] = d0; dr[br][1] = d1; dr[br][2] = d2;
      float dot = qlv0 * d0 + qlv1 * d1 + qlv2 * d2;
      lvl[br] = rdl63(wsum63(dot)) * invs;
    }
    // wave-local level softmax
    float mx = fmaxf(lvl[0], fmaxf(lvl[1], lvl[2]));
    float e0 = __expf(lvl[0] - mx), e1 = __expf(lvl[1] - mx), e2 = __expf(lvl[2] - mx);
    float inv = 1.f / (e0 + e1 + e2);
    float w0 = e0 * inv, w1v = e1 * inv, w2v = e2 * inv;
    float a0 = w0 * dr[0][0] + w1v * dr[1][0] + w2v * dr[2][0];
    float a1 = w0 * dr[0][1] + w1v * dr[1][1] + w2v * dr[2][1];
    float a2 = w0 * dr[0][2] + w1v * dr[1][2] + w2v * dr[2][2];
    float dot = qwv0 * a0 + qwv1 * a1 + qwv2 * a2;
    float tw = wsum63(dot);
    if (lane == 63) tl[l] = tw * invs;
    at0[nw] = a0; at1[nw] = a1; at2[nw] = a2; myl[nw] = l; ++nw;
  }
  __syncthreads();

  // ---- phase 2a: word softmax ONCE (wave 0), normalized weights -> tl ----
  if (wave == 0){
    float v = (lane < 30) ? tl[lane] : -1e30f;
    float mx = rdl63(wmax63(v));
    float e = (lane < 30) ? __expf(v - mx) : 0.f;
    float den = rdl63(wsum63(e));
    if (lane < 30) tl[lane] = e / den;
  }
  __syncthreads();

  // ---- phase 2b: weighted combine + per-wave partials ----
  float p0 = 0.f, p1 = 0.f, p2 = 0.f;
  for (int q = 0; q < nw; ++q){
    float wwv = tl[myl[q]];
    p0 += wwv * at0[q]; p1 += wwv * at1[q]; p2 += wwv * at2[q];
  }
  pbuf[wave][lane] = p0;
  pbuf[wave][lane + 64] = p1;
  if (has2) pbuf[wave][lane + 128] = p2;
  __syncthreads();
  if (tid < 150){
    float acc = 0.f;
    #pragma unroll
    for (int w = 0; w < 8; ++w) acc += pbuf[w][tid];
    outp[tid] = acc;
  }
}

// ---------------- K4: scores -> logits -> log_softmax (LDS-staged) ----------------
__global__ __launch_bounds__(256) void final_k(const float* __restrict__ rc, const float* __restrict__ rh,
                                               const float* __restrict__ lw, const float* __restrict__ lb,
                                               float* __restrict__ out){
  __shared__ float Cl[750];
  __shared__ float Hl[7500];
  __shared__ float sc[5][52];
  __shared__ float lg[5];
  const int b = blockIdx.x, tid = threadIdx.x;
  const float* C = rc + b * 750;
  const float* H = rh + (size_t)b * 7500;
  for (int i = tid; i < 750; i += 256) Cl[i] = C[i];
  for (int i = tid; i < 7500; i += 256) Hl[i] = H[i];
  __syncthreads();
  if (tid < 250){
    int c = tid / 50, h = tid % 50;
    float s = 0.f;
    #pragma unroll 10
    for (int k = 0; k < 150; ++k) s += Cl[c * 150 + k] * Hl[h * 150 + k];
    sc[c][h] = s;
  }
  __syncthreads();
  if (tid < 5){
    float s = lb[0];
    for (int h = 0; h < 50; ++h) s += sc[tid][h] * lw[h];
    lg[tid] = s;
  }
  __syncthreads();
  if (tid < 5){
    float mx = fmaxf(fmaxf(fmaxf(lg[0], lg[1]), fmaxf(lg[2], lg[3])), lg[4]);
    float den = 0.f;
    for (int c = 0; c < 5; ++c) den += expf(lg[c] - mx);
    out[b * 5 + tid] = lg[tid] - mx - logf(den);
  }
}

extern "C" void kernel_launch(void* const* d_in, const int* in_sizes, int n_in,
                              void* d_out, int out_size, void* d_ws, size_t ws_size,
                              hipStream_t stream){
  const int*   cand = (const int*)d_in[0];
  const int*   clk  = (const int*)d_in[1];
  const float* emb  = (const float*)d_in[2];
  const float* w1   = (const float*)d_in[3];
  const float* b1   = (const float*)d_in[4];
  const float* w2   = (const float*)d_in[5];
  const float* b2   = (const float*)d_in[6];
  const float* w3   = (const float*)d_in[7];
  const float* b3   = (const float*)d_in[8];
  const float* lng  = (const float*)d_in[9];
  const float* lnb  = (const float*)d_in[10];
  const float* ql   = (const float*)d_in[11];
  const float* qw   = (const float*)d_in[12];
  const float* lw   = (const float*)d_in[13];
  const float* lb   = (const float*)d_in[14];
  float* out = (float*)d_out;

  char* ws = (char*)d_ws;
  const size_t szA = (size_t)M_TILES * KT * 16384;  // 32,112,640 B
  const size_t szB = (size_t)12 * KT * 8192;        //     983,040 B
  const size_t szT = (size_t)M_ROWS * TROW * 2;     // 140,800,000 B
  u16*   A  = (u16*)ws;
  u16*   B  = (u16*)(ws + szA);
  u16*   T  = (u16*)(ws + szA + szB);
  float* rc = (float*)(ws + szA + szB + szT);
  float* rh = rc + 320 * 150;

  build_A<<<(M_PAD * 40 + 255) / 256, 256, 0, stream>>>(emb, A);
  build_B<<<(N_PAD * K_PAD + 255) / 256, 256, 0, stream>>>(w1, w2, w3, B);
  gemm_k<<<dim3(N_TILES, M_TILES), 512, 0, stream>>>(A, B, T);
  encode_k<<<3520, 512, 0, stream>>>(cand, clk, T, b1, b2, b3, lng, lnb, ql, qw, rc, rh);
  final_k<<<64, 256, 0, stream>>>(rc, rh, lw, lb, out);
}